// Round 1
// 247.153 us; speedup vs baseline: 1.0125x; 1.0125x over previous
//
#include <hip/hip_runtime.h>

#define DIM   32
#define HID   64
#define TILES 8              // 16-cell tiles per wave
#define HPAD  72             // h LDS row stride in bf16 (144 B, 16B-aligned)
#define HBUF  (16 * HPAD)    // one h buffer (shorts) per wave

typedef __attribute__((ext_vector_type(8))) short bf16x8;   // 8 bf16 = 4 VGPRs
typedef __attribute__((ext_vector_type(4))) float f32x4;

// hardware packed f32x2 -> bf16x2 (RNE), result is one VGPR = 2 bf16 lanes
__device__ __forceinline__ unsigned cvt_pk_bf16(float lo, float hi) {
    unsigned r;
    asm("v_cvt_pk_bf16_f32 %0, %1, %2" : "=v"(r) : "v"(lo), "v"(hi));
    return r;
}

union bfu { bf16x8 v; unsigned u[4]; };

__global__ __launch_bounds__(256) void behavior_mfma(
    const float* __restrict__ g_in,   // [N, 32]
    const float* __restrict__ pot,    // [N]
    const float* __restrict__ W1,     // [33, 64]
    const float* __restrict__ b1,     // [64]
    const float* __restrict__ W2,     // [64, 32]
    const float* __restrict__ b2,     // [32]
    float* __restrict__ out)          // [N, 32]
{
    // per-wave DOUBLE-buffered h tile: 2 x [16 cells][HPAD bf16]
    __shared__ __align__(16) short sH[4 * 2 * HBUF];

    const int tid  = threadIdx.x;
    const int lane = tid & 63;
    const int quad = lane >> 4;        // 0..3
    const int mrow = lane & 15;        // 0..15
    const int wave = tid >> 6;         // 0..3
    short* hb = &sH[wave * 2 * HBUF];

    // ---- B-fragments: W1 (K=32), 4 n-chunks. B[k= quad*8+j][n= nb*16+mrow] ----
    bf16x8 w1f[4];
    float  w1p[4], b1v[4];
    #pragma unroll
    for (int nb = 0; nb < 4; ++nb) {
        bfu t;
        #pragma unroll
        for (int jp = 0; jp < 4; ++jp)
            t.u[jp] = cvt_pk_bf16(W1[(quad * 8 + 2 * jp)     * HID + nb * 16 + mrow],
                                  W1[(quad * 8 + 2 * jp + 1) * HID + nb * 16 + mrow]);
        w1f[nb] = t.v;
        w1p[nb] = W1[32 * HID + nb * 16 + mrow];
        b1v[nb] = b1[nb * 16 + mrow];
    }
    // ---- B-fragments: W2 (2 k-chunks x 2 n-chunks) ----
    bf16x8 w2f[2][2];
    #pragma unroll
    for (int kc = 0; kc < 2; ++kc)
        #pragma unroll
        for (int nc = 0; nc < 2; ++nc) {
            bfu t;
            #pragma unroll
            for (int jp = 0; jp < 4; ++jp)
                t.u[jp] = cvt_pk_bf16(W2[(kc * 32 + quad * 8 + 2 * jp)     * DIM + nc * 16 + mrow],
                                      W2[(kc * 32 + quad * 8 + 2 * jp + 1) * DIM + nc * 16 + mrow]);
            w2f[kc][nc] = t.v;
        }
    float b2v[2];
    #pragma unroll
    for (int nc = 0; nc < 2; ++nc) b2v[nc] = b2[nc * 16 + mrow];

    // ---- identity B-fragment for the 0.3*g pass-through (pure integer build) ----
    bf16x8 idf[2];
    #pragma unroll
    for (int nc = 0; nc < 2; ++nc) {
        bfu t;
        #pragma unroll
        for (int jp = 0; jp < 4; ++jp) {
            unsigned lo = (quad * 8 + 2 * jp     == nc * 16 + mrow) ? 0x00003F80u : 0u;
            unsigned hi = (quad * 8 + 2 * jp + 1 == nc * 16 + mrow) ? 0x3F800000u : 0u;
            t.u[jp] = lo | hi;
        }
        idf[nc] = t.v;
    }

    const long cell0 = ((long)blockIdx.x * 4 + wave) * (TILES * 16);

    // ---------- pipeline helpers ----------
    auto loadTile = [&](long cb, float4& a, float4& b, float4& p) {
        const float* gp = g_in + (cb + mrow) * DIM + quad * 8;
        a = ((const float4*)gp)[0];
        b = ((const float4*)gp)[1];
        p = *(const float4*)(pot + cb + quad * 4);
    };

    // norm + GEMM1 + h->LDS(buf) + produce gf (0.3g A-frag)
    auto stageA = [&](const float4& a, const float4& b, const float4& p,
                      short* buf, bf16x8& gf_out) {
        float gv[8] = {a.x, a.y, a.z, a.w, b.x, b.y, b.z, b.w};
        float cube[8];
        float tp = 0.f, sp = 0.f;
        #pragma unroll
        for (int j = 0; j < 8; ++j) {
            float gc = gv[j];
            float g2 = gc * gc;
            float g3 = g2 * gc;
            tp += g2;
            sp = fmaf(g3, g3, sp);
            cube[j] = g3;
        }
        tp += __shfl_xor(tp, 16, 64); tp += __shfl_xor(tp, 32, 64);
        sp += __shfl_xor(sp, 16, 64); sp += __shfl_xor(sp, 32, 64);
        const float scale = 0.1f * __builtin_amdgcn_sqrtf(tp) *
                            __builtin_amdgcn_rcpf(__builtin_amdgcn_sqrtf(sp) + 1e-8f);

        bfu xf, gf;
        #pragma unroll
        for (int jp = 0; jp < 4; ++jp) {
            xf.u[jp] = cvt_pk_bf16(fmaf(scale, cube[2 * jp],     gv[2 * jp]),
                                   fmaf(scale, cube[2 * jp + 1], gv[2 * jp + 1]));
            gf.u[jp] = cvt_pk_bf16(0.3f * gv[2 * jp], 0.3f * gv[2 * jp + 1]);
        }
        gf_out = gf.v;

        const float pvr[4] = {p.x, p.y, p.z, p.w};
        #pragma unroll
        for (int nb = 0; nb < 4; ++nb) {
            f32x4 c1;
            #pragma unroll
            for (int r = 0; r < 4; ++r) c1[r] = fmaf(pvr[r], w1p[nb], b1v[nb]);
            c1 = __builtin_amdgcn_mfma_f32_16x16x32_bf16(xf.v, w1f[nb], c1, 0, 0, 0);
            // packed relu+cvt: rows (quad*4 .. quad*4+3), col nb*16+mrow
            unsigned p01 = cvt_pk_bf16(fmaxf(c1[0], 0.f), fmaxf(c1[1], 0.f));
            unsigned p23 = cvt_pk_bf16(fmaxf(c1[2], 0.f), fmaxf(c1[3], 0.f));
            short* bp = &buf[(quad * 4) * HPAD + nb * 16 + mrow];
            bp[0 * HPAD] = (short)(p01);
            bp[1 * HPAD] = (short)(p01 >> 16);   // ds_write_b16_d16_hi
            bp[2 * HPAD] = (short)(p23);
            bp[3 * HPAD] = (short)(p23 >> 16);
        }
    };

    auto gemm2 = [&](const bf16x8& hf0, const bf16x8& hf1, const bf16x8& gfv, long cb) {
        #pragma unroll
        for (int nc = 0; nc < 2; ++nc) {
            f32x4 c2 = {b2v[nc], b2v[nc], b2v[nc], b2v[nc]};
            c2 = __builtin_amdgcn_mfma_f32_16x16x32_bf16(gfv, idf[nc],    c2, 0, 0, 0);
            c2 = __builtin_amdgcn_mfma_f32_16x16x32_bf16(hf0, w2f[0][nc], c2, 0, 0, 0);
            c2 = __builtin_amdgcn_mfma_f32_16x16x32_bf16(hf1, w2f[1][nc], c2, 0, 0, 0);
            #pragma unroll
            for (int r = 0; r < 4; ++r)
                out[(cb + quad * 4 + r) * DIM + nc * 16 + mrow] = c2[r];
        }
    };

    // ---------- 2-stage software pipeline over tiles ----------
    float4 cga, cgb, cpv, nga, ngb, npv;
    bf16x8 gfP, gfC;

    loadTile(cell0, cga, cgb, cpv);
    loadTile(cell0 + 16, nga, ngb, npv);
    stageA(cga, cgb, cpv, hb, gfP);                     // tile 0 -> buf 0

    #pragma unroll 2
    for (int t = 1; t < TILES; ++t) {
        // 1) issue ds_reads for h(t-1) early — latency hidden by stageA(t)
        short* rbuf = hb + ((t - 1) & 1) * HBUF;
        bf16x8 hf0 = *(const bf16x8*)&rbuf[mrow * HPAD +  0 + quad * 8];
        bf16x8 hf1 = *(const bf16x8*)&rbuf[mrow * HPAD + 32 + quad * 8];

        // 2) rotate prefetch regs, issue global loads for tile t+1
        cga = nga; cgb = ngb; cpv = npv;
        if (t + 1 < TILES)
            loadTile(cell0 + (long)(t + 1) * 16, nga, ngb, npv);

        // 3) stage A for tile t (norm + GEMM1 + ds_write into other buffer)
        stageA(cga, cgb, cpv, hb + (t & 1) * HBUF, gfC);

        // 4) stage B for tile t-1 (GEMM2 + store)
        gemm2(hf0, hf1, gfP, cell0 + (long)(t - 1) * 16);
        gfP = gfC;
    }

    // epilogue: stage B for the last tile
    {
        short* rbuf = hb + ((TILES - 1) & 1) * HBUF;
        bf16x8 hf0 = *(const bf16x8*)&rbuf[mrow * HPAD +  0 + quad * 8];
        bf16x8 hf1 = *(const bf16x8*)&rbuf[mrow * HPAD + 32 + quad * 8];
        gemm2(hf0, hf1, gfP, cell0 + (long)(TILES - 1) * 16);
    }
}

extern "C" void kernel_launch(void* const* d_in, const int* in_sizes, int n_in,
                              void* d_out, int out_size, void* d_ws, size_t ws_size,
                              hipStream_t stream) {
    const float* g_in = (const float*)d_in[0];
    const float* pot  = (const float*)d_in[1];
    const float* W1   = (const float*)d_in[2];
    const float* b1   = (const float*)d_in[3];
    const float* W2   = (const float*)d_in[4];
    const float* b2   = (const float*)d_in[5];
    float* out = (float*)d_out;

    const int n_cells = in_sizes[1];                     // 1048576
    const int cells_per_block = 4 * TILES * 16;          // 512
    const int blocks = (n_cells + cells_per_block - 1) / cells_per_block;

    behavior_mfma<<<blocks, 256, 0, stream>>>(g_in, pot, W1, b1, W2, b2, out);
}